// Round 15
// baseline (96.943 us; speedup 1.0000x reference)
//
#include <hip/hip_runtime.h>
#include <stdint.h>

// BinarizeLinear: out[i][j] = sum_k sign(x[i][k]) * sign(W[j][k]) + bias[j]
// R15 = R13 skeleton (MX-FP4 exact +-1; 128x256 block, 64x64/wave, 48 KB LDS,
// 3 gl_lds/wave, vmcnt(3) counted prefetch — proven 82.6 µs) with the MFMA
// shape swapped to 32x32x64 f8f6f4 (9099 TOPS vs 7228; 4x MACs per fragment
// byte; half the MFMA instructions; same 64 acc regs).  R14's 128x64-wave
// variant regressed (reg pressure ~250) and is reverted.
// LDS is FRAGMENT-MAJOR: each 1 KB block = one 32x32x64 operand fragment in
// exact lane order; fragment read = ds_read_b128 @ frag*1024 + lane*16
// (stride-16, conflict-floor). gl_lds keeps a linear dest; the permutation
// lives in the per-lane GLOBAL source address (m173 pattern):
//   lane l of frag (rb,ksl): row rb*32+(l&31), byte kt*64+ksl*32+(l>>5)*16.
// Exact: A and B use the same lane->(line,k) mapping (ISA-symmetric), both
// packed k-ascending -> k-pairing cancels; f32 accum of int sums <= 2048.
// C/D 32x32: col=lane&31, row=(r&3)+8*(r>>2)+4*(lane>>5) (m74/m101).

#define Mdim 16384
#define Ndim 2048
#define Kdim 2048
#define NT 16  // K-tiles of 128 fp4 (64 B rows)

using i32x4 = __attribute__((ext_vector_type(4))) int;
using i32x8 = __attribute__((ext_vector_type(8))) int;
using f32x16 = __attribute__((ext_vector_type(16))) float;

// Binarize f32 -> packed fp4 (+1=0x2, -1=0xA), 16 f32 -> 8 bytes per thread.
__global__ __launch_bounds__(256) void binarize_fp4(const float* __restrict__ x,
                                                    const float* __restrict__ w,
                                                    uint8_t* __restrict__ out,
                                                    int nx16, int ntot16) {
  int i = blockIdx.x * 256 + threadIdx.x;
  if (i >= ntot16) return;
  const float4* p = (i < nx16) ? ((const float4*)x + (size_t)i * 4)
                               : ((const float4*)w + (size_t)(i - nx16) * 4);
  float4 f0 = p[0], f1 = p[1], f2 = p[2], f3 = p[3];
  float s[16] = {f0.x, f0.y, f0.z, f0.w, f1.x, f1.y, f1.z, f1.w,
                 f2.x, f2.y, f2.z, f2.w, f3.x, f3.y, f3.z, f3.w};
  union { uint8_t b[8]; uint2 v; } u;
#pragma unroll
  for (int j = 0; j < 8; ++j) {
    const unsigned lo = s[2 * j] > 0.0f ? 0x2u : 0xAu;
    const unsigned hi = s[2 * j + 1] > 0.0f ? 0x2u : 0xAu;
    u.b[j] = (uint8_t)(lo | (hi << 4));
  }
  ((uint2*)out)[i] = u.v;  // xb4 then wb4, contiguous
}

__device__ __forceinline__ void gl_lds16(const void* gsrc, void* ldst) {
  __builtin_amdgcn_global_load_lds(
      (const __attribute__((address_space(1))) void*)gsrc,
      (__attribute__((address_space(3))) void*)ldst, 16, 0, 0);
}

__device__ __forceinline__ i32x8 dup8(i32x4 v) {
  i32x8 r;
  r[0] = v[0]; r[1] = v[1]; r[2] = v[2]; r[3] = v[3];
  r[4] = v[0]; r[5] = v[1]; r[6] = v[2]; r[7] = v[3];  // fp4 uses regs [0:3]
  return r;
}

__global__ __launch_bounds__(512, 1) void bin_gemm_fp4_32(const uint8_t* __restrict__ A4,
                                                          const uint8_t* __restrict__ W4,
                                                          const float* __restrict__ bias,
                                                          float* __restrict__ C) {
  // Fragment-major LDS. A: 8 frags (4 rowblocks x 2 ksl), B: 16 frags. 48 KB.
  __shared__ __align__(16) uint8_t As[2][8 * 1024];
  __shared__ __align__(16) uint8_t Bs[2][16 * 1024];

  const int tid = threadIdx.x;
  const int lane = tid & 63;
  const int wid = tid >> 6;  // 0..7
  const int wm = wid >> 2;   // 0..1 (M half: 64 rows)
  const int wn = wid & 3;    // 0..3 (N quarter: 64 cols)

  // XCD swizzle: 1024 blocks, %8==0 -> bijective; the 8 A-panel sharers are
  // co-XCD (L2 reuse of xb4).
  const int bid = blockIdx.x;
  const int swz = (bid & 7) * 128 + (bid >> 3);
  const long brow = (long)(swz >> 3) * 128;  // 128 M-panels
  const long bcol = (long)(swz & 7) * 256;   // 8 col-tiles

  const long rowBytes = Kdim / 2;  // 1024 B per logical row

  // Per-lane source-offset pieces for fragment staging:
  // lane l -> row-in-block (l&31), 16B half (l>>5).
  const int lrow = lane & 31;
  const int lkh = (lane >> 5) * 16;

  // This wave stages fragments wid*3 .. wid*3+2 (24 total: A 0-7, B 8-23).
  // Fragment fi<8: A rowblock fi>>1, ksl fi&1 -> dest As[buf][fi*1024].
  // Fragment fi>=8: fj=fi-8, B rowblock fj>>1, ksl fj&1 -> Bs[buf][fj*1024].

  f32x16 acc[2][2] = {};  // 64 regs
  i32x4 a[2][2], b[2][2];  // [blk][ksl]

#define BAR() asm volatile("s_barrier" ::: "memory")
#define STAGE(BUF, KT)                                                                 \
  do {                                                                                 \
    _Pragma("unroll") for (int j_ = 0; j_ < 3; ++j_) {                                 \
      const int fi_ = wid * 3 + j_;                                                    \
      if (fi_ < 8) {                                                                   \
        const int rb_ = fi_ >> 1, ks_ = fi_ & 1;                                       \
        const uint8_t* s_ = A4 + (brow + rb_ * 32 + lrow) * rowBytes +                 \
                            ((long)(KT) << 6) + ks_ * 32 + lkh;                        \
        gl_lds16(s_, &As[BUF][fi_ * 1024]);                                            \
      } else {                                                                         \
        const int fj_ = fi_ - 8;                                                       \
        const int rb_ = fj_ >> 1, ks_ = fj_ & 1;                                       \
        const uint8_t* s_ = W4 + (bcol + rb_ * 32 + lrow) * rowBytes +                 \
                            ((long)(KT) << 6) + ks_ * 32 + lkh;                        \
        gl_lds16(s_, &Bs[BUF][fj_ * 1024]);                                            \
      }                                                                                \
    }                                                                                  \
  } while (0)

  // ---- prologue: stage tiles 0,1 (3 gl_lds/wave each); tile0 resident.
  STAGE(0, 0);
  STAGE(1, 1);
  asm volatile("s_waitcnt vmcnt(3)" ::: "memory");
  BAR();

#pragma unroll 1
  for (int t = 0; t < NT; ++t) {
    const int cur = t & 1;

    // fragment reads (8 x ds_read_b128 @ frag*1024 + lane*16), drain pre-BAR
#pragma unroll
    for (int blk = 0; blk < 2; ++blk)
#pragma unroll
      for (int ks = 0; ks < 2; ++ks) {
        a[blk][ks] = *(const i32x4*)&As[cur][((wm * 2 + blk) * 2 + ks) * 1024 + lane * 16];
        b[blk][ks] = *(const i32x4*)&Bs[cur][((wn * 2 + blk) * 2 + ks) * 1024 + lane * 16];
      }
    asm volatile("s_waitcnt lgkmcnt(0)" ::: "memory");
    BAR();  // all waves done reading buf cur

    // overwrite cur with tile t+2 (post-barrier: safe)
    if (t + 2 < NT) STAGE(cur, t + 2);

    __builtin_amdgcn_s_setprio(1);
#pragma unroll
    for (int frb = 0; frb < 2; ++frb)
#pragma unroll
      for (int fcb = 0; fcb < 2; ++fcb)
#pragma unroll
        for (int ks = 0; ks < 2; ++ks) {
          // cbsz=4 (A=fp4), blgp=4 (B=fp4); scales E8M0 0x7F = 1.0 (exact).
          acc[frb][fcb] = __builtin_amdgcn_mfma_scale_f32_32x32x64_f8f6f4(
              dup8(a[frb][ks]), dup8(b[fcb][ks]), acc[frb][fcb], 4, 4, 0, 0x7F7F7F7F,
              0, 0x7F7F7F7F);
        }
    __builtin_amdgcn_s_setprio(0);

    // retire tile t+1's stages (3 newest = tile t+2's, just issued)
    if (t < NT - 2) {
      asm volatile("s_waitcnt vmcnt(3)" ::: "memory");
    } else {
      asm volatile("s_waitcnt vmcnt(0)" ::: "memory");
    }
    BAR();
  }

  // ---- epilogue: 32x32 C/D: col=lane&31, row=(r&3)+8*(r>>2)+4*(lane>>5) ----
#pragma unroll
  for (int fcb = 0; fcb < 2; ++fcb) {
    const long col = bcol + wn * 64 + fcb * 32 + (lane & 31);
    const float bj = bias[col];
#pragma unroll
    for (int frb = 0; frb < 2; ++frb) {
      const long rbase = brow + wm * 64 + frb * 32 + (lane >> 5) * 4;
#pragma unroll
      for (int r = 0; r < 16; ++r) {
        const long row = rbase + (r & 3) + 8 * (r >> 2);
        C[row * (long)Ndim + col] = acc[frb][fcb][r] + bj;
      }
    }
  }
#undef BAR
#undef STAGE
}

extern "C" void kernel_launch(void* const* d_in, const int* in_sizes, int n_in,
                              void* d_out, int out_size, void* d_ws, size_t ws_size,
                              hipStream_t stream) {
  const float* x = (const float*)d_in[0];
  const float* w = (const float*)d_in[1];
  const float* bias = (const float*)d_in[2];
  float* out = (float*)d_out;

  uint8_t* xb4 = (uint8_t*)d_ws;                 // 16.8 MB (fp4-packed)
  uint8_t* wb4 = xb4 + (size_t)Mdim * Kdim / 2;  // + 2.1 MB (ws >= 18.9 MB)

  const int nx16 = Mdim * Kdim / 16;  // 16-f32 units
  const int nw16 = Ndim * Kdim / 16;
  const int ntot16 = nx16 + nw16;
  binarize_fp4<<<(ntot16 + 255) / 256, 256, 0, stream>>>(x, w, xb4, nx16, ntot16);

  dim3 grid((Mdim / 128) * (Ndim / 256));  // 1024 blocks, %8==0
  bin_gemm_fp4_32<<<grid, 512, 0, stream>>>(xb4, wb4, bias, out);
}

// Round 16
// 89.691 us; speedup vs baseline: 1.0809x; 1.0809x over previous
//
#include <hip/hip_runtime.h>
#include <stdint.h>

// BinarizeLinear: out[i][j] = sum_k sign(x[i][k]) * sign(W[j][k]) + bias[j]
// R16: R3's hardware-verified 8-phase 256x256 schedule, ported to MX-FP4.
// Identical byte geometry (K-tile = 256 fp4 = 128 B rows; slot^(row&7) swizzle;
// vmcnt(6) counted prefetch; phase-shifted stage ledger) -- only the MFMA is
// mfma_scale_f32_16x16x128_f8f6f4 (R13's proven-exact arg form), NT=8, f32 acc,
// fenced barriers (R6 lesson), ext8 = undef-high widen (fp4 ignores regs 4..7).
// Rationale: R13's 2-phase GEMM = 36% of fp4 ubench = the documented 2-barrier
// structure ceiling; bytes no longer bind (LDS ~20, HBM ~24, MFMA ~19 µs);
// m201 shows 8-phase breaks this ceiling (+35-40%).
// Exact: fp4 e2m1 +-1 (0x2/0xA), scale E8M0 0x7F=1.0, f32 accum, sums <= 2048.

#define Mdim 16384
#define Ndim 2048
#define Kdim 2048
#define NT 8  // K-tiles of 256 fp4 (128 B)

using i32x4 = __attribute__((ext_vector_type(4))) int;
using i32x8 = __attribute__((ext_vector_type(8))) int;
using f32x4 = __attribute__((ext_vector_type(4))) float;

// Binarize f32 -> packed fp4 (+1=0x2, -1=0xA), 16 f32 -> 8 bytes per thread.
__global__ __launch_bounds__(256) void binarize_fp4(const float* __restrict__ x,
                                                    const float* __restrict__ w,
                                                    uint8_t* __restrict__ out,
                                                    int nx16, int ntot16) {
  int i = blockIdx.x * 256 + threadIdx.x;
  if (i >= ntot16) return;
  const float4* p = (i < nx16) ? ((const float4*)x + (size_t)i * 4)
                               : ((const float4*)w + (size_t)(i - nx16) * 4);
  float4 f0 = p[0], f1 = p[1], f2 = p[2], f3 = p[3];
  float s[16] = {f0.x, f0.y, f0.z, f0.w, f1.x, f1.y, f1.z, f1.w,
                 f2.x, f2.y, f2.z, f2.w, f3.x, f3.y, f3.z, f3.w};
  union { uint8_t b[8]; uint2 v; } u;
#pragma unroll
  for (int j = 0; j < 8; ++j) {
    const unsigned lo = s[2 * j] > 0.0f ? 0x2u : 0xAu;
    const unsigned hi = s[2 * j + 1] > 0.0f ? 0x2u : 0xAu;
    u.b[j] = (uint8_t)(lo | (hi << 4));
  }
  ((uint2*)out)[i] = u.v;  // xb4 then wb4, contiguous
}

__device__ __forceinline__ void gl_lds16(const void* gsrc, void* ldst) {
  __builtin_amdgcn_global_load_lds(
      (const __attribute__((address_space(1))) void*)gsrc,
      (__attribute__((address_space(3))) void*)ldst, 16, 0, 0);
}

// fp4 f8f6f4 reads only regs [0:3] of the 8-reg operand: high half undef.
__device__ __forceinline__ i32x8 ext8(i32x4 v) {
  return __builtin_shufflevector(v, v, 0, 1, 2, 3, -1, -1, -1, -1);
}

__global__ __launch_bounds__(512, 1) void bin_gemm_fp4_8ph(const uint8_t* __restrict__ A4,
                                                           const uint8_t* __restrict__ W4,
                                                           const float* __restrict__ bias,
                                                           float* __restrict__ C) {
  // [dbuf][half][128 rows][128 B]; 64 KiB per matrix, 128 KiB total.
  __shared__ __align__(16) uint8_t As[2][2][128 * 128];
  __shared__ __align__(16) uint8_t Bs[2][2][128 * 128];

  const int tid = threadIdx.x;
  const int lane = tid & 63;
  const int wid = tid >> 6;  // 0..7
  const int wm = wid >> 2;   // 0..1
  const int wn = wid & 3;    // 0..3

  // XCD swizzle: 512 blocks, %8==0 -> bijective.
  const int bid = blockIdx.x;
  const int swz = (bid & 7) * 64 + (bid >> 3);
  const long brow = (long)(swz >> 3) * 256;  // 64 row-tiles
  const long bcol = (long)(swz & 7) * 256;   // 8 col-tiles

  const long rowBytes = Kdim / 2;  // 1024 B per logical row

  // ---- staging: linear LDS dest, pre-swizzled global source slot (R3) ----
  const int srow = wid * 16 + (lane >> 3);            // q=0 row-in-half (q=1: +8)
  const int sgcol = ((lane & 7) ^ (lane >> 3)) * 16;  // slot ^ (row&7)

  // ---- fragment ds_read byte offsets (swizzled read: slot ^ (row&7)) ----
  int offA[4][2], offB[2][2];
#pragma unroll
  for (int fr = 0; fr < 4; ++fr) {
    const int ra = wm * 64 + fr * 16 + (lane & 15);
#pragma unroll
    for (int ksl = 0; ksl < 2; ++ksl) {
      const int s = ksl * 4 + (lane >> 4);
      offA[fr][ksl] = ra * 128 + ((s ^ (ra & 7)) * 16);
    }
  }
#pragma unroll
  for (int fc = 0; fc < 2; ++fc) {
    const int rb = wn * 32 + fc * 16 + (lane & 15);
#pragma unroll
    for (int ksl = 0; ksl < 2; ++ksl) {
      const int s = ksl * 4 + (lane >> 4);
      offB[fc][ksl] = rb * 128 + ((s ^ (rb & 7)) * 16);
    }
  }

  f32x4 acc[2][4][2][2] = {};  // [mh][fr][nh][fc] -- 64 regs
  i32x4 a[4][2];               // current-mh A frags
  i32x4 b0[2][2], b1[2][2];    // B-h0 held P1..P4; B-h1 held P2..P3

#define BAR() asm volatile("s_barrier" ::: "memory")
#define STAGE_A(DB, H, KT)                                                               \
  do {                                                                                   \
    const uint8_t* s0_ = A4 + (brow + (H)*128 + srow) * rowBytes + ((long)(KT) << 7) +   \
                         sgcol;                                                          \
    gl_lds16(s0_, &As[DB][H][(wid * 16 + 0) * 128]);                                     \
    gl_lds16(s0_ + 8 * rowBytes, &As[DB][H][(wid * 16 + 8) * 128]);                      \
  } while (0)
#define STAGE_B(DB, H, KT)                                                               \
  do {                                                                                   \
    const uint8_t* s0_ = W4 + (bcol + (H)*128 + srow) * rowBytes + ((long)(KT) << 7) +   \
                         sgcol;                                                          \
    gl_lds16(s0_, &Bs[DB][H][(wid * 16 + 0) * 128]);                                     \
    gl_lds16(s0_ + 8 * rowBytes, &Bs[DB][H][(wid * 16 + 8) * 128]);                      \
  } while (0)
#define LOAD_A(DB, H)                                        \
  _Pragma("unroll") for (int fr = 0; fr < 4; ++fr)           \
  _Pragma("unroll") for (int ksl = 0; ksl < 2; ++ksl)        \
      a[fr][ksl] = *(const i32x4*)&As[DB][H][offA[fr][ksl]];
#define LOAD_B(DB, H, BB)                                    \
  _Pragma("unroll") for (int fc = 0; fc < 2; ++fc)           \
  _Pragma("unroll") for (int ksl = 0; ksl < 2; ++ksl)        \
      BB[fc][ksl] = *(const i32x4*)&Bs[DB][H][offB[fc][ksl]];
#define MFMA16(MH, NH, BB)                                                      \
  __builtin_amdgcn_s_setprio(1);                                                \
  _Pragma("unroll") for (int fr = 0; fr < 4; ++fr)                              \
  _Pragma("unroll") for (int fc = 0; fc < 2; ++fc)                              \
  _Pragma("unroll") for (int ksl = 0; ksl < 2; ++ksl)                           \
      acc[MH][fr][NH][fc] = __builtin_amdgcn_mfma_scale_f32_16x16x128_f8f6f4(   \
          ext8(a[fr][ksl]), ext8(BB[fc][ksl]), acc[MH][fr][NH][fc], 4, 4, 0,    \
          0x7F7F7F7F, 0, 0x7F7F7F7F);                                           \
  __builtin_amdgcn_s_setprio(0);
#define SYNC_PRE()                                     \
  BAR();                                               \
  asm volatile("s_waitcnt lgkmcnt(0)" ::: "memory");   \
  __builtin_amdgcn_sched_barrier(0)

  // ---- prologue: tile 0 full (8 loads) + tile 1 A-h0/B-h1/A-h1 (6 loads).
  // Tile 1's B-h0 is staged in iter-0 P1. vmcnt(6) -> tile 0 resident.
  STAGE_A(0, 0, 0); STAGE_A(0, 1, 0); STAGE_B(0, 0, 0); STAGE_B(0, 1, 0);
  STAGE_A(1, 0, 1); STAGE_B(1, 1, 1); STAGE_A(1, 1, 1);
  asm volatile("s_waitcnt vmcnt(6)" ::: "memory");
  BAR();

#pragma unroll 1
  for (int t = 0; t < NT; ++t) {
    const int db = t & 1;
    const bool pf1 = (t + 1 < NT);
    const bool pf2 = (t + 2 < NT);

    // P1: reads A-h0 + B-h0 (dbuf db); stage B-h0(t+1)->Bs[db^1][0]
    //     (last read of Bs[db^1][0] was iter t-1 P4 -- barrier-separated)
    LOAD_A(db, 0);
    LOAD_B(db, 0, b0);
    if (pf1) STAGE_B(db ^ 1, 0, t + 1);
    SYNC_PRE();
    MFMA16(0, 0, b0);
    BAR();

    // P2: reads B-h1; stage A-h0(t+2)->As[db][0] (last read: P1)
    LOAD_B(db, 1, b1);
    if (pf2) STAGE_A(db, 0, t + 2);
    SYNC_PRE();
    MFMA16(0, 1, b1);
    BAR();

    // P3: reads A-h1; stage B-h1(t+2)->Bs[db][1] (last read: P2)
    LOAD_A(db, 1);
    if (pf2) STAGE_B(db, 1, t + 2);
    SYNC_PRE();
    MFMA16(1, 1, b1);
    BAR();

    // P4: no LDS reads (b0 held from P1); stage A-h1(t+2)->As[db][1]
    //     (last read: P3)
    if (pf2) STAGE_A(db, 1, t + 2);
    SYNC_PRE();
    MFMA16(1, 0, b0);
    // Boundary: newest 6 outstanding = tile t+2 stages (P2-P4); everything
    // older (incl. P1's tile t+1 B-h0) retired by vmcnt(6).
    if (t < NT - 2) {
      asm volatile("s_waitcnt vmcnt(6)" ::: "memory");
    } else {
      asm volatile("s_waitcnt vmcnt(0)" ::: "memory");
    }
    BAR();
  }

  // ---- epilogue: C/D layout col=lane&15, row=(lane>>4)*4+reg ----
#pragma unroll
  for (int nh = 0; nh < 2; ++nh) {
#pragma unroll
    for (int fc = 0; fc < 2; ++fc) {
      const long col = bcol + nh * 128 + wn * 32 + fc * 16 + (lane & 15);
      const float bj = bias[col];
#pragma unroll
      for (int mh = 0; mh < 2; ++mh) {
#pragma unroll
        for (int fr = 0; fr < 4; ++fr) {
          const long row0 = brow + mh * 128 + wm * 64 + fr * 16 + (lane >> 4) * 4;
#pragma unroll
          for (int r = 0; r < 4; ++r) {
            C[(row0 + r) * (long)Ndim + col] = acc[mh][fr][nh][fc][r] + bj;
          }
        }
      }
    }
  }
#undef BAR
#undef STAGE_A
#undef STAGE_B
#undef LOAD_A
#undef LOAD_B
#undef MFMA16
#undef SYNC_PRE
}

extern "C" void kernel_launch(void* const* d_in, const int* in_sizes, int n_in,
                              void* d_out, int out_size, void* d_ws, size_t ws_size,
                              hipStream_t stream) {
  const float* x = (const float*)d_in[0];
  const float* w = (const float*)d_in[1];
  const float* bias = (const float*)d_in[2];
  float* out = (float*)d_out;

  uint8_t* xb4 = (uint8_t*)d_ws;                 // 16.8 MB (fp4-packed)
  uint8_t* wb4 = xb4 + (size_t)Mdim * Kdim / 2;  // + 2.1 MB (ws >= 18.9 MB)

  const int nx16 = Mdim * Kdim / 16;  // 16-f32 units
  const int nw16 = Ndim * Kdim / 16;
  const int ntot16 = nx16 + nw16;
  binarize_fp4<<<(ntot16 + 255) / 256, 256, 0, stream>>>(x, w, xb4, nx16, ntot16);

  dim3 grid((Mdim / 256) * (Ndim / 256));  // 512 blocks, %8==0
  bin_gemm_fp4_8ph<<<grid, 512, 0, stream>>>(xb4, wb4, bias, out);
}